// Round 3
// baseline (82.683 us; speedup 1.0000x reference)
//
#include <hip/hip_runtime.h>
#include <math.h>

// (B,T,N,D) = (16,100,128,3), fp32 in, fp32 scalar out.
constexpr int B = 16, T = 100, N = 128;
constexpr float MIN_DIST  = 0.05f;
constexpr float MIN_DIST2 = MIN_DIST * MIN_DIST;

constexpr int THREADS      = 256;
constexpr int PEN_BLOCKS   = B * T;               // 1600 — one block per (b,t) slice
constexpr int MISC_BLOCKS  = 160;
constexpr int TOTAL_BLOCKS = PEN_BLOCKS + MISC_BLOCKS;

constexpr int PER_B = T * N * 3;                  // 38400 floats per batch
constexpr int PER_T = N * 3;                      // 384 floats per slice

// misc work decomposition (work term is elementwise over contiguous ranges)
constexpr int WORK_V4_PER_B = (T - 1) * N * 3 / 4;    // 9504 float4 per batch
constexpr int WORK_V4 = B * WORK_V4_PER_B;            // 152064
constexpr int KE_V4_PER_SLICE = N * 3 / 4;            // 96
constexpr int KE_V4  = 2 * B * KE_V4_PER_SLICE;       // 3072
constexpr int STAB_V = B * 5 * N;                     // 10240 norm vectors
constexpr int MISC_TOTAL = WORK_V4 + STAB_V + KE_V4;  // 165376

constexpr int WORK_N = B * (T - 1) * N;           // 202752 (mean divisor)

// ws layout (every slot written every call -> no zero-init node):
constexpr int WORK_OFF = 1600, STAB_OFF = 1760, KE0_OFF = 1920, KE1_OFF = 2080;

__device__ __forceinline__ float wave_sum(float v) {
#pragma unroll
    for (int off = 32; off > 0; off >>= 1) v += __shfl_down(v, off, 64);
    return v;
}

__global__ __launch_bounds__(THREADS) void physics_fused(
    const float* __restrict__ traj, const float* __restrict__ vel,
    const float* __restrict__ frc, float* __restrict__ ws)
{
    __shared__ float4 spos[N];
    __shared__ float  red[4][4];

    const int tid  = threadIdx.x;
    const int bid  = blockIdx.x;
    const int lane = tid & 63;
    const int wv   = tid >> 6;

    if (bid < PEN_BLOCKS) {
        // ---- penetration: one (b,t) slice; lane owns points l and l+64 ----
        const float* p = traj + (size_t)bid * PER_T;
        for (int k = tid; k < N; k += THREADS)
            spos[k] = make_float4(p[k * 3], p[k * 3 + 1], p[k * 3 + 2], 0.f);
        __syncthreads();

        const float4 pa = spos[lane];
        const float4 pb = spos[lane + 64];
        const int jbase = wv * 32;                 // wave sweeps its j-quarter
        float s = 0.f;
#pragma unroll 8
        for (int jj = 0; jj < 32; ++jj) {
            const int j = jbase + jj;              // wave-uniform -> LDS broadcast
            const float4 pj = spos[j];
            float dx = pa.x - pj.x, dy = pa.y - pj.y, dz = pa.z - pj.z;
            float d2 = dx * dx + dy * dy + dz * dz;
            if (d2 < MIN_DIST2 && j != lane)          s += MIN_DIST - sqrtf(d2);
            dx = pb.x - pj.x; dy = pb.y - pj.y; dz = pb.z - pj.z;
            d2 = dx * dx + dy * dy + dz * dz;
            if (d2 < MIN_DIST2 && j != lane + 64)     s += MIN_DIST - sqrtf(d2);
        }
        float w = wave_sum(s);
        if (lane == 0) red[0][wv] = w;
        __syncthreads();
        if (tid == 0)
            ws[bid] = 0.5f * (red[0][0] + red[0][1] + red[0][2] + red[0][3]);
    } else {
        // ---- work / stability / kinetic: vectorized grid-stride ----
        const int mb = bid - PEN_BLOCKS;
        const float4* t4 = (const float4*)traj;
        const float4* f4 = (const float4*)frc;
        const float4* v4 = (const float4*)vel;
        float sw = 0.f, ss = 0.f, k0 = 0.f, k1 = 0.f;
        const int stride = MISC_BLOCKS * THREADS;
        for (int v = mb * THREADS + tid; v < MISC_TOTAL; v += stride) {
            if (v < WORK_V4) {
                // elementwise: frc[b,t,:,:]*(traj[b,t+1]-traj[b,t]), contiguous per b
                const int b = v / WORK_V4_PER_B;
                const int r = v - b * WORK_V4_PER_B;
                const int base = b * (PER_B / 4) + r;
                const float4 f  = f4[base];
                const float4 t0 = t4[base];
                const float4 t1 = t4[base + PER_T / 4];
                sw += f.x * (t1.x - t0.x) + f.y * (t1.y - t0.y)
                    + f.z * (t1.z - t0.z) + f.w * (t1.w - t0.w);
            } else if (v < WORK_V4 + STAB_V) {
                const int s2 = v - WORK_V4;
                const int b  = s2 / 640;           // 5*N vectors per batch
                const int r  = s2 - b * 640;
                const int e  = b * PER_B + 95 * PER_T + r * 3;
                const float vx = vel[e], vy = vel[e + 1], vz = vel[e + 2];
                ss += sqrtf(vx * vx + vy * vy + vz * vz);
            } else {
                const int s2    = v - WORK_V4 - STAB_V;      // [0,3072)
                const int which = s2 / 1536;                 // 0 -> t=0, 1 -> t=T-1
                const int rr    = s2 - which * 1536;
                const int b     = rr / KE_V4_PER_SLICE;
                const int r     = rr - b * KE_V4_PER_SLICE;
                const float4 q  = v4[b * (PER_B / 4) + which * (99 * PER_T / 4) + r];
                const float k   = q.x * q.x + q.y * q.y + q.z * q.z + q.w * q.w;
                if (which) k1 += k; else k0 += k;
            }
        }
        float vals[4] = {sw, ss, k0, k1};
#pragma unroll
        for (int vv = 0; vv < 4; ++vv) {
            float w = wave_sum(vals[vv]);
            if (lane == 0) red[vv][wv] = w;
        }
        __syncthreads();
        if (tid == 0) {
            ws[WORK_OFF + mb] = red[0][0] + red[0][1] + red[0][2] + red[0][3];
            ws[STAB_OFF + mb] = red[1][0] + red[1][1] + red[1][2] + red[1][3];
            ws[KE0_OFF  + mb] = red[2][0] + red[2][1] + red[2][2] + red[2][3];
            ws[KE1_OFF  + mb] = red[3][0] + red[3][1] + red[3][2] + red[3][3];
        }
    }
}

__global__ __launch_bounds__(256) void physics_finalize(
    const float* __restrict__ ws, float* __restrict__ out)
{
    __shared__ float redP[4], redM[4];
    const int tid = threadIdx.x, lane = tid & 63, wv = tid >> 6;

    float p = 0.f;
    for (int i = tid; i < PEN_BLOCKS; i += 256) p += ws[i];

    const int base = WORK_OFF + 160 * wv;   // wave wv: work/stab/ke0/ke1 segment
    float m = ws[base + lane] + ws[base + 64 + lane]
            + (lane < 32 ? ws[base + 128 + lane] : 0.f);

    p = wave_sum(p);
    m = wave_sum(m);
    if (lane == 0) { redP[wv] = p; redM[wv] = m; }
    __syncthreads();

    if (tid == 0) {
        const float pen = redP[0] + redP[1] + redP[2] + redP[3];
        const float wk = redM[0], st = redM[1], k0 = redM[2], k1 = redM[3];
        const float pen_loss  = pen / (float)((long long)B * T * (N * (N - 1) / 2));
        const float stab_loss = st / (float)STAB_V;
        const float ke_s = 0.5f * k0 / (float)(B * N);
        const float ke_e = 0.5f * k1 / (float)(B * N);
        const float work = wk / (float)WORK_N;
        out[0] = 10.0f * pen_loss + stab_loss + 0.1f * fabsf(ke_e - ke_s - work);
    }
}

extern "C" void kernel_launch(void* const* d_in, const int* in_sizes, int n_in,
                              void* d_out, int out_size, void* d_ws, size_t ws_size,
                              hipStream_t stream) {
    const float* traj = (const float*)d_in[0];
    const float* vel  = (const float*)d_in[1];
    const float* frc  = (const float*)d_in[2];
    float* out = (float*)d_out;
    float* ws  = (float*)d_ws;

    physics_fused<<<TOTAL_BLOCKS, THREADS, 0, stream>>>(traj, vel, frc, ws);
    physics_finalize<<<1, 256, 0, stream>>>(ws, out);
}

// Round 4
// 69.810 us; speedup vs baseline: 1.1844x; 1.1844x over previous
//
#include <hip/hip_runtime.h>
#include <math.h>

// (B,T,N,D) = (16,100,128,3), fp32 in, fp32 scalar out.
constexpr int B = 16, T = 100, N = 128;
constexpr float MIN_DIST  = 0.05f;
constexpr float MIN_DIST2 = MIN_DIST * MIN_DIST;

constexpr int THREADS      = 256;
constexpr int PEN_BLOCKS   = B * T;               // 1600 — one block per (b,t) slice
constexpr int MISC_BLOCKS  = 160;
constexpr int TOTAL_BLOCKS = PEN_BLOCKS + MISC_BLOCKS;

constexpr int PER_B = T * N * 3;                  // 38400 floats per batch
constexpr int PER_T = N * 3;                      // 384 floats per slice

// misc work decomposition (work term is elementwise over contiguous ranges)
constexpr int WORK_V4_PER_B = (T - 1) * N * 3 / 4;    // 9504 float4 per batch
constexpr int WORK_V4 = B * WORK_V4_PER_B;            // 152064
constexpr int KE_V4_PER_SLICE = N * 3 / 4;            // 96
constexpr int KE_V4  = 2 * B * KE_V4_PER_SLICE;       // 3072
constexpr int STAB_V = B * 5 * N;                     // 10240 norm vectors
constexpr int MISC_TOTAL = WORK_V4 + STAB_V + KE_V4;  // 165376

constexpr int WORK_N = B * (T - 1) * N;           // 202752 (mean divisor)

// ws layout (every slot written every call -> no zero-init node):
constexpr int WORK_OFF = 1600, STAB_OFF = 1760, KE0_OFF = 1920, KE1_OFF = 2080;

__device__ __forceinline__ float wave_sum(float v) {
#pragma unroll
    for (int off = 32; off > 0; off >>= 1) v += __shfl_down(v, off, 64);
    return v;
}

__global__ __launch_bounds__(THREADS) void physics_fused(
    const float* __restrict__ traj, const float* __restrict__ vel,
    const float* __restrict__ frc, float* __restrict__ ws)
{
    __shared__ float4 spos[N];
    __shared__ float  red[4][4];

    const int tid  = threadIdx.x;
    const int bid  = blockIdx.x;
    const int lane = tid & 63;
    const int wv   = tid >> 6;

    if (bid < PEN_BLOCKS) {
        // ---- penetration: one (b,t) slice; lane owns points l and l+64 ----
        const float* p = traj + (size_t)bid * PER_T;
        for (int k = tid; k < N; k += THREADS)
            spos[k] = make_float4(p[k * 3], p[k * 3 + 1], p[k * 3 + 2], 0.f);
        __syncthreads();

        const float4 pa = spos[lane];
        const float4 pb = spos[lane + 64];
        const int jbase = wv * 32;                 // wave sweeps its j-quarter
        float s = 0.f;
#pragma unroll 8
        for (int jj = 0; jj < 32; ++jj) {
            const int j = jbase + jj;              // wave-uniform -> LDS broadcast
            const float4 pj = spos[j];
            const float dxa = pa.x - pj.x, dya = pa.y - pj.y, dza = pa.z - pj.z;
            const float d2a = dxa * dxa + dya * dya + dza * dza;
            const float dxb = pb.x - pj.x, dyb = pb.y - pj.y, dzb = pb.z - pj.z;
            const float d2b = dxb * dxb + dyb * dyb + dzb * dzb;
            const bool ha = (d2a < MIN_DIST2) & (j != lane);
            const bool hb = (d2b < MIN_DIST2) & (j != lane + 64);
            // hits are ~1e-5/pair: make the sqrt path a wave-coherent skip
            if (__builtin_expect(__any(ha | hb), 0)) {
                if (ha) s += MIN_DIST - sqrtf(d2a);
                if (hb) s += MIN_DIST - sqrtf(d2b);
            }
        }
        float w = wave_sum(s);
        if (lane == 0) red[0][wv] = w;
        __syncthreads();
        if (tid == 0)
            ws[bid] = 0.5f * (red[0][0] + red[0][1] + red[0][2] + red[0][3]);
    } else {
        // ---- work / stability / kinetic: vectorized grid-stride ----
        const int mb = bid - PEN_BLOCKS;
        const float4* t4 = (const float4*)traj;
        const float4* f4 = (const float4*)frc;
        const float4* v4 = (const float4*)vel;
        float sw = 0.f, ss = 0.f, k0 = 0.f, k1 = 0.f;
        const int stride = MISC_BLOCKS * THREADS;
        for (int v = mb * THREADS + tid; v < MISC_TOTAL; v += stride) {
            if (v < WORK_V4) {
                // elementwise: frc[b,t,:,:]*(traj[b,t+1]-traj[b,t]), contiguous per b
                const int b = v / WORK_V4_PER_B;
                const int r = v - b * WORK_V4_PER_B;
                const int base = b * (PER_B / 4) + r;
                const float4 f  = f4[base];
                const float4 t0 = t4[base];
                const float4 t1 = t4[base + PER_T / 4];
                sw += f.x * (t1.x - t0.x) + f.y * (t1.y - t0.y)
                    + f.z * (t1.z - t0.z) + f.w * (t1.w - t0.w);
            } else if (v < WORK_V4 + STAB_V) {
                const int s2 = v - WORK_V4;
                const int b  = s2 / 640;           // 5*N vectors per batch
                const int r  = s2 - b * 640;
                const int e  = b * PER_B + 95 * PER_T + r * 3;
                const float vx = vel[e], vy = vel[e + 1], vz = vel[e + 2];
                ss += sqrtf(vx * vx + vy * vy + vz * vz);
            } else {
                const int s2    = v - WORK_V4 - STAB_V;      // [0,3072)
                const int which = s2 / 1536;                 // 0 -> t=0, 1 -> t=T-1
                const int rr    = s2 - which * 1536;
                const int b     = rr / KE_V4_PER_SLICE;
                const int r     = rr - b * KE_V4_PER_SLICE;
                const float4 q  = v4[b * (PER_B / 4) + which * (99 * PER_T / 4) + r];
                const float k   = q.x * q.x + q.y * q.y + q.z * q.z + q.w * q.w;
                if (which) k1 += k; else k0 += k;
            }
        }
        float vals[4] = {sw, ss, k0, k1};
#pragma unroll
        for (int vv = 0; vv < 4; ++vv) {
            float w = wave_sum(vals[vv]);
            if (lane == 0) red[vv][wv] = w;
        }
        __syncthreads();
        if (tid == 0) {
            ws[WORK_OFF + mb] = red[0][0] + red[0][1] + red[0][2] + red[0][3];
            ws[STAB_OFF + mb] = red[1][0] + red[1][1] + red[1][2] + red[1][3];
            ws[KE0_OFF  + mb] = red[2][0] + red[2][1] + red[2][2] + red[2][3];
            ws[KE1_OFF  + mb] = red[3][0] + red[3][1] + red[3][2] + red[3][3];
        }
    }
}

__global__ __launch_bounds__(256) void physics_finalize(
    const float* __restrict__ ws, float* __restrict__ out)
{
    __shared__ float redP[4], redM[4];
    const int tid = threadIdx.x, lane = tid & 63, wv = tid >> 6;

    float p = 0.f;
    for (int i = tid; i < PEN_BLOCKS; i += 256) p += ws[i];

    const int base = WORK_OFF + 160 * wv;   // wave wv: work/stab/ke0/ke1 segment
    float m = ws[base + lane] + ws[base + 64 + lane]
            + (lane < 32 ? ws[base + 128 + lane] : 0.f);

    p = wave_sum(p);
    m = wave_sum(m);
    if (lane == 0) { redP[wv] = p; redM[wv] = m; }
    __syncthreads();

    if (tid == 0) {
        const float pen = redP[0] + redP[1] + redP[2] + redP[3];
        const float wk = redM[0], st = redM[1], k0 = redM[2], k1 = redM[3];
        const float pen_loss  = pen / (float)((long long)B * T * (N * (N - 1) / 2));
        const float stab_loss = st / (float)STAB_V;
        const float ke_s = 0.5f * k0 / (float)(B * N);
        const float ke_e = 0.5f * k1 / (float)(B * N);
        const float work = wk / (float)WORK_N;
        out[0] = 10.0f * pen_loss + stab_loss + 0.1f * fabsf(ke_e - ke_s - work);
    }
}

extern "C" void kernel_launch(void* const* d_in, const int* in_sizes, int n_in,
                              void* d_out, int out_size, void* d_ws, size_t ws_size,
                              hipStream_t stream) {
    const float* traj = (const float*)d_in[0];
    const float* vel  = (const float*)d_in[1];
    const float* frc  = (const float*)d_in[2];
    float* out = (float*)d_out;
    float* ws  = (float*)d_ws;

    physics_fused<<<TOTAL_BLOCKS, THREADS, 0, stream>>>(traj, vel, frc, ws);
    physics_finalize<<<1, 256, 0, stream>>>(ws, out);
}

// Round 5
// 67.419 us; speedup vs baseline: 1.2264x; 1.0355x over previous
//
#include <hip/hip_runtime.h>
#include <math.h>

// (B,T,N,D) = (16,100,128,3), fp32 in, fp32 scalar out.
constexpr int B = 16, T = 100, N = 128;
constexpr float MIN_DIST  = 0.05f;
constexpr float MIN_DIST2 = MIN_DIST * MIN_DIST;

constexpr int THREADS      = 256;
constexpr int PEN_BLOCKS   = B * T;               // 1600 — one block per (b,t) slice
constexpr int MISC_BLOCKS  = 160;                 // scheduled FIRST for overlap
constexpr int TOTAL_BLOCKS = PEN_BLOCKS + MISC_BLOCKS;

constexpr int PER_B = T * N * 3;                  // 38400 floats per batch
constexpr int PER_T = N * 3;                      // 384 floats per slice

// misc work decomposition (work term is elementwise over contiguous ranges)
constexpr int WORK_V4_PER_B = (T - 1) * N * 3 / 4;    // 9504 float4 per batch
constexpr int WORK_V4 = B * WORK_V4_PER_B;            // 152064
constexpr int KE_V4_PER_SLICE = N * 3 / 4;            // 96
constexpr int KE_V4  = 2 * B * KE_V4_PER_SLICE;       // 3072
constexpr int STAB_V = B * 5 * N;                     // 10240 norm vectors
constexpr int MISC_TOTAL = WORK_V4 + STAB_V + KE_V4;  // 165376

constexpr int WORK_N = B * (T - 1) * N;           // 202752 (mean divisor)

// ws layout (every slot written every call -> no zero-init node):
constexpr int WORK_OFF = 1600, STAB_OFF = 1760, KE0_OFF = 1920, KE1_OFF = 2080;

__device__ __forceinline__ float wave_sum(float v) {
#pragma unroll
    for (int off = 32; off > 0; off >>= 1) v += __shfl_down(v, off, 64);
    return v;
}

__global__ __launch_bounds__(THREADS) void physics_fused(
    const float* __restrict__ traj, const float* __restrict__ vel,
    const float* __restrict__ frc, float* __restrict__ ws)
{
    __shared__ float4 spos[N];
    __shared__ float  sraw[PER_T];   // 384 floats, coalesced-staged
    __shared__ float  red[4][4];

    const int tid  = threadIdx.x;
    const int bid  = blockIdx.x;
    const int lane = tid & 63;
    const int wv   = tid >> 6;

    if (bid >= MISC_BLOCKS) {
        // ---- penetration: one (b,t) slice, unordered pairs only ----
        const int pb = bid - MISC_BLOCKS;
        // stage: 96 coalesced float4 loads -> LDS raw
        if (tid < PER_T / 4)
            ((float4*)sraw)[tid] = ((const float4*)traj)[pb * (PER_T / 4) + tid];
        __syncthreads();
        // repack to one float4 per point (b128-friendly compute reads)
        if (tid < N)
            spos[tid] = make_float4(sraw[tid * 3], sraw[tid * 3 + 1], sraw[tid * 3 + 2], 0.f);
        __syncthreads();

        // wrap partition: i = tid&127; half0 -> k=1..32, half1 -> k=33..63 (+k=64, i<64)
        const int i    = tid & (N - 1);
        const int half = tid >> 7;
        const float4 pi = spos[i];
        float s = 0.f;
        const int k0 = 1 + half * 32;
        const int k1 = 32 + half * 31;             // half0: 1..32, half1: 33..63
#pragma unroll 8
        for (int k = k0; k <= k1; ++k) {
            const int j = (i + k) & (N - 1);       // stride-1 across lanes
            const float4 pj = spos[j];
            const float dx = pi.x - pj.x, dy = pi.y - pj.y, dz = pi.z - pj.z;
            const float d2 = dx * dx + dy * dy + dz * dz;
            const bool h = d2 < MIN_DIST2;
            if (__builtin_expect(__any(h), 0))     // hits ~1e-5/pair
                if (h) s += MIN_DIST - sqrtf(d2);
        }
        if (half) {                                // k = 64 diagonal, count once
            const float4 pj = spos[(i + 64) & (N - 1)];
            const float dx = pi.x - pj.x, dy = pi.y - pj.y, dz = pi.z - pj.z;
            const float d2 = dx * dx + dy * dy + dz * dz;
            const bool h = (d2 < MIN_DIST2) & (i < 64);
            if (__builtin_expect(__any(h), 0))
                if (h) s += MIN_DIST - sqrtf(d2);
        }
        float w = wave_sum(s);
        if (lane == 0) red[0][wv] = w;
        __syncthreads();
        if (tid == 0)
            ws[pb] = red[0][0] + red[0][1] + red[0][2] + red[0][3];
    } else {
        // ---- work / stability / kinetic: vectorized grid-stride ----
        const int mb = bid;
        const float4* t4 = (const float4*)traj;
        const float4* f4 = (const float4*)frc;
        const float4* v4 = (const float4*)vel;
        float sw = 0.f, ss = 0.f, k0 = 0.f, k1 = 0.f;
        const int stride = MISC_BLOCKS * THREADS;
        for (int v = mb * THREADS + tid; v < MISC_TOTAL; v += stride) {
            if (v < WORK_V4) {
                const int b = v / WORK_V4_PER_B;
                const int r = v - b * WORK_V4_PER_B;
                const int base = b * (PER_B / 4) + r;
                const float4 f  = f4[base];
                const float4 t0 = t4[base];
                const float4 t1 = t4[base + PER_T / 4];
                sw += f.x * (t1.x - t0.x) + f.y * (t1.y - t0.y)
                    + f.z * (t1.z - t0.z) + f.w * (t1.w - t0.w);
            } else if (v < WORK_V4 + STAB_V) {
                const int s2 = v - WORK_V4;
                const int b  = s2 / 640;           // 5*N vectors per batch
                const int r  = s2 - b * 640;
                const int e  = b * PER_B + 95 * PER_T + r * 3;
                const float vx = vel[e], vy = vel[e + 1], vz = vel[e + 2];
                ss += sqrtf(vx * vx + vy * vy + vz * vz);
            } else {
                const int s2    = v - WORK_V4 - STAB_V;      // [0,3072)
                const int which = s2 / 1536;                 // 0 -> t=0, 1 -> t=T-1
                const int rr    = s2 - which * 1536;
                const int b     = rr / KE_V4_PER_SLICE;
                const int r     = rr - b * KE_V4_PER_SLICE;
                const float4 q  = v4[b * (PER_B / 4) + which * (99 * PER_T / 4) + r];
                const float k   = q.x * q.x + q.y * q.y + q.z * q.z + q.w * q.w;
                if (which) k1 += k; else k0 += k;
            }
        }
        float vals[4] = {sw, ss, k0, k1};
#pragma unroll
        for (int vv = 0; vv < 4; ++vv) {
            float w = wave_sum(vals[vv]);
            if (lane == 0) red[vv][wv] = w;
        }
        __syncthreads();
        if (tid == 0) {
            ws[WORK_OFF + mb] = red[0][0] + red[0][1] + red[0][2] + red[0][3];
            ws[STAB_OFF + mb] = red[1][0] + red[1][1] + red[1][2] + red[1][3];
            ws[KE0_OFF  + mb] = red[2][0] + red[2][1] + red[2][2] + red[2][3];
            ws[KE1_OFF  + mb] = red[3][0] + red[3][1] + red[3][2] + red[3][3];
        }
    }
}

__global__ __launch_bounds__(256) void physics_finalize(
    const float* __restrict__ ws, float* __restrict__ out)
{
    __shared__ float redP[4], redM[4];
    const int tid = threadIdx.x, lane = tid & 63, wv = tid >> 6;

    float p = 0.f;
    for (int i = tid; i < PEN_BLOCKS; i += 256) p += ws[i];

    const int base = WORK_OFF + 160 * wv;   // wave wv: work/stab/ke0/ke1 segment
    float m = ws[base + lane] + ws[base + 64 + lane]
            + (lane < 32 ? ws[base + 128 + lane] : 0.f);

    p = wave_sum(p);
    m = wave_sum(m);
    if (lane == 0) { redP[wv] = p; redM[wv] = m; }
    __syncthreads();

    if (tid == 0) {
        const float pen = redP[0] + redP[1] + redP[2] + redP[3];  // unordered-pair sum
        const float wk = redM[0], st = redM[1], k0 = redM[2], k1 = redM[3];
        const float pen_loss  = pen / (float)((long long)B * T * (N * (N - 1) / 2));
        const float stab_loss = st / (float)STAB_V;
        const float ke_s = 0.5f * k0 / (float)(B * N);
        const float ke_e = 0.5f * k1 / (float)(B * N);
        const float work = wk / (float)WORK_N;
        out[0] = 10.0f * pen_loss + stab_loss + 0.1f * fabsf(ke_e - ke_s - work);
    }
}

extern "C" void kernel_launch(void* const* d_in, const int* in_sizes, int n_in,
                              void* d_out, int out_size, void* d_ws, size_t ws_size,
                              hipStream_t stream) {
    const float* traj = (const float*)d_in[0];
    const float* vel  = (const float*)d_in[1];
    const float* frc  = (const float*)d_in[2];
    float* out = (float*)d_out;
    float* ws  = (float*)d_ws;

    physics_fused<<<TOTAL_BLOCKS, THREADS, 0, stream>>>(traj, vel, frc, ws);
    physics_finalize<<<1, 256, 0, stream>>>(ws, out);
}